// Round 1
// baseline (364.638 us; speedup 1.0000x reference)
//
#include <hip/hip_runtime.h>
#include <hip/hip_bf16.h>

// Problem dims
#define BB 64
#define TT 128
#define FIN 12
#define HH 128
#define GG 512  // 4*H

#define LOG2E 1.4426950408889634f
#define TWO_LOG2E 2.8853900817779268f

__device__ __forceinline__ float fexp2(float x) { return __builtin_amdgcn_exp2f(x); }
__device__ __forceinline__ float frcp(float x)  { return __builtin_amdgcn_rcpf(x); }

// tanh(x) = 1 - 2/(1+e^{2x}); correct limits at +/-inf via exp2->{inf,0}
__device__ __forceinline__ float tanh_f(float x) {
  return 1.0f - 2.0f * frcp(1.0f + fexp2(TWO_LOG2E * x));
}
__device__ __forceinline__ float sigm_f(float x) {
  return frcp(1.0f + fexp2(-LOG2E * x));
}

#define FMA4S(acc, s, v) do { \
  acc.x = fmaf((s), (v).x, acc.x); \
  acc.y = fmaf((s), (v).y, acc.y); \
  acc.z = fmaf((s), (v).z, acc.z); \
  acc.w = fmaf((s), (v).w, acc.w); } while (0)

// ---------------------------------------------------------------------------
// K1: encoder + decoder LSTM. One block per batch element. 512 threads,
// thread g owns gate row g (Whh row in 128 VGPRs). h broadcast from LDS.
// ---------------------------------------------------------------------------
__global__ __launch_bounds__(512, 2) void lstm_kernel(
    const float* __restrict__ x,
    const float* __restrict__ eWih, const float* __restrict__ eWhh, const float* __restrict__ eb,
    const float* __restrict__ dWih, const float* __restrict__ dWhh, const float* __restrict__ db,
    float* __restrict__ encH, float* __restrict__ decH)
{
  const int b = blockIdx.x;
  const int g = threadIdx.x;  // 0..511

  __shared__ __align__(16) float xs[TT * FIN];   // 6 KB
  __shared__ __align__(16) float h_lds[HH];
  __shared__ __align__(16) float zact[GG];

  // stage this batch's input sequence
  if (g < (TT * FIN / 4))
    ((float4*)xs)[g] = ((const float4*)(x + (size_t)b * TT * FIN))[g];
  if (g < HH) h_lds[g] = 0.0f;
  float c = 0.0f;  // valid for g < 128

  const int gate = g >> 7;

  #pragma unroll 1
  for (int phase = 0; phase < 2; ++phase) {
    const float* Wih  = phase ? dWih : eWih;
    const float* Whh  = phase ? dWhh : eWhh;
    const float* bias = phase ? db : eb;
    float* Hout       = phase ? decH : encH;

    // per-thread weights into registers
    float wih[FIN];
    #pragma unroll
    for (int j = 0; j < 3; ++j) {
      float4 v = *(const float4*)(Wih + g * FIN + 4 * j);
      wih[4*j+0] = v.x; wih[4*j+1] = v.y; wih[4*j+2] = v.z; wih[4*j+3] = v.w;
    }
    float whh[HH];
    #pragma unroll
    for (int j = 0; j < 32; ++j) {
      float4 v = *(const float4*)(Whh + g * HH + 4 * j);
      whh[4*j+0] = v.x; whh[4*j+1] = v.y; whh[4*j+2] = v.z; whh[4*j+3] = v.w;
    }
    const float bz = bias[g];

    #pragma unroll 1
    for (int t = 0; t < TT; ++t) {
      __syncthreads();  // h_lds (and xs first iter) ready; zact reads of prev iter done
      float a0 = bz, a1 = 0.0f, a2 = 0.0f, a3 = 0.0f;
      {
        const float4* xt4 = (const float4*)(xs + t * FIN);
        float4 xa = xt4[0], xb = xt4[1], xc = xt4[2];
        a0 = fmaf(xa.x, wih[0], a0); a1 = fmaf(xa.y, wih[1], a1);
        a2 = fmaf(xa.z, wih[2], a2); a3 = fmaf(xa.w, wih[3], a3);
        a0 = fmaf(xb.x, wih[4], a0); a1 = fmaf(xb.y, wih[5], a1);
        a2 = fmaf(xb.z, wih[6], a2); a3 = fmaf(xb.w, wih[7], a3);
        a0 = fmaf(xc.x, wih[8], a0); a1 = fmaf(xc.y, wih[9], a1);
        a2 = fmaf(xc.z, wih[10], a2); a3 = fmaf(xc.w, wih[11], a3);
      }
      #pragma unroll
      for (int k = 0; k < HH; k += 4) {
        float4 h4 = *(const float4*)&h_lds[k];  // broadcast read
        a0 = fmaf(h4.x, whh[k + 0], a0);
        a1 = fmaf(h4.y, whh[k + 1], a1);
        a2 = fmaf(h4.z, whh[k + 2], a2);
        a3 = fmaf(h4.w, whh[k + 3], a3);
      }
      float acc = (a0 + a1) + (a2 + a3);
      zact[g] = (gate == 2) ? tanh_f(acc) : sigm_f(acc);
      __syncthreads();  // zact ready
      if (g < HH) {
        float iv = zact[g], fv = zact[HH + g], gv = zact[2 * HH + g], ov = zact[3 * HH + g];
        c = fmaf(fv, c, iv * gv);
        float hn = ov * tanh_f(c);
        h_lds[g] = hn;
        Hout[((size_t)b * TT + t) * HH + g] = hn;
      }
    }
  }
}

// ---------------------------------------------------------------------------
// K2: A[b,s,h] = decH[b,s,:]·W1[h,:] + attn_b[h]   (m==0)
//     P[b,t,h] = encH[b,t,:]·W2[h,:]               (m==1)
// grid 1024 = (8 row-tiles x 64 b x 2 m), 256 threads, k-halved LDS W^T.
// ---------------------------------------------------------------------------
__global__ __launch_bounds__(256, 2) void proj_kernel(
    const float* __restrict__ encH, const float* __restrict__ decH,
    const float* __restrict__ attnW, const float* __restrict__ attnb,
    float* __restrict__ Abuf, float* __restrict__ Pbuf)
{
  const int m  = blockIdx.x & 1;
  const int b  = (blockIdx.x >> 1) & 63;
  const int r0 = (blockIdx.x >> 7) * 16;
  const int tid = threadIdx.x;

  __shared__ __align__(16) float WT[64 * 128];  // 32 KB: W^T for a k-half
  __shared__ __align__(16) float Xt[16 * 128];  // 8 KB

  const float* X = (m ? encH : decH) + ((size_t)b * TT + r0) * HH;
  const float* W = attnW + (m ? HH : 0);

  ((float4*)Xt)[tid]       = ((const float4*)X)[tid];
  ((float4*)Xt)[256 + tid] = ((const float4*)X)[256 + tid];

  const int hq = tid & 31, rr = tid >> 5;
  const int h0 = 4 * hq;

  float4 acc0, acc1;
  if (m == 0) { acc0 = *(const float4*)(attnb + h0); acc1 = acc0; }
  else        { acc0 = make_float4(0.f, 0.f, 0.f, 0.f); acc1 = acc0; }

  for (int kb = 0; kb < 2; ++kb) {
    __syncthreads();  // protect WT overwrite
    {
      int h = tid >> 1, koff = (tid & 1) * 32;
      #pragma unroll
      for (int j = 0; j < 8; ++j) {
        float4 v = *(const float4*)(W + h * 256 + kb * 64 + koff + 4 * j);
        int kp = koff + 4 * j;
        WT[(kp + 0) * 128 + h] = v.x;
        WT[(kp + 1) * 128 + h] = v.y;
        WT[(kp + 2) * 128 + h] = v.z;
        WT[(kp + 3) * 128 + h] = v.w;
      }
    }
    __syncthreads();
    const float* xr0 = Xt + (2 * rr) * 128 + kb * 64;
    const float* xr1 = xr0 + 128;
    #pragma unroll
    for (int k4 = 0; k4 < 64; k4 += 4) {
      float4 xa = *(const float4*)(xr0 + k4);
      float4 xb = *(const float4*)(xr1 + k4);
      float4 w0 = *(const float4*)&WT[(k4 + 0) * 128 + h0];
      float4 w1 = *(const float4*)&WT[(k4 + 1) * 128 + h0];
      float4 w2 = *(const float4*)&WT[(k4 + 2) * 128 + h0];
      float4 w3 = *(const float4*)&WT[(k4 + 3) * 128 + h0];
      FMA4S(acc0, xa.x, w0); FMA4S(acc0, xa.y, w1);
      FMA4S(acc0, xa.z, w2); FMA4S(acc0, xa.w, w3);
      FMA4S(acc1, xb.x, w0); FMA4S(acc1, xb.y, w1);
      FMA4S(acc1, xb.z, w2); FMA4S(acc1, xb.w, w3);
    }
  }
  float* O = (m ? Pbuf : Abuf) + ((size_t)b * TT + r0) * HH;
  *(float4*)(O + (2 * rr) * 128 + h0)     = acc0;
  *(float4*)(O + (2 * rr + 1) * 128 + h0) = acc1;
}

// ---------------------------------------------------------------------------
// K3: attention + output. Block = (b, 16 decoder steps). 512 threads.
// t halved so LDS stays < 64 KB; P transposed into LDS with XOR-quad swizzle.
// ---------------------------------------------------------------------------
__global__ __launch_bounds__(512, 2) void attn_kernel(
    const float* __restrict__ encH, const float* __restrict__ decH,
    const float* __restrict__ Abuf, const float* __restrict__ Pbuf,
    const float* __restrict__ vw, const float* __restrict__ outW,
    const float* __restrict__ outb, float* __restrict__ out)
{
  const int b  = blockIdx.x >> 3;
  const int s0 = (blockIdx.x & 7) * 16;
  const int tid = threadIdx.x;

  __shared__ __align__(16) float buf[64 * 128];    // 32 KB: P^T-half (swizzled), later encH-half
  __shared__ __align__(16) float a_lds[16 * 128];  // 8 KB: A tile, later ctx
  __shared__ __align__(16) float sc[16 * 128];     // 8 KB: scores -> weights
  __shared__ __align__(16) float dh[16 * 128];     // 8 KB: decH tile
  __shared__ __align__(16) float vl[HH];

  ((float4*)a_lds)[tid] = ((const float4*)(Abuf + ((size_t)b * TT + s0) * HH))[tid];
  ((float4*)dh)[tid]    = ((const float4*)(decH + ((size_t)b * TT + s0) * HH))[tid];
  if (tid < 32) ((float4*)vl)[tid] = ((const float4*)vw)[tid];

  const int u  = tid & 31;
  const int sl = tid >> 5;   // 0..15 decoder-step within tile
  const int uq = u & 15;     // t-quad within half
  const int uh = u >> 4;     // 0/1 h-half

  // ---- energies/scores ----
  for (int half = 0; half < 2; ++half) {
    const int tbase = half * 64;
    __syncthreads();  // prev buf use done (also covers initial staging)
    #pragma unroll
    for (int i = 0; i < 4; ++i) {
      int flat = i * 2048 + tid * 4;
      int tp = flat >> 7;        // 0..63
      int h0 = flat & 127;
      float4 v = *(const float4*)(Pbuf + ((size_t)b * TT + tbase + tp) * HH + h0);
      int tq = tp >> 2, tr = tp & 3;
      buf[(h0 + 0) * 64 + 4 * ((tq ^ ((h0 + 0) >> 2)) & 15) + tr] = v.x;
      buf[(h0 + 1) * 64 + 4 * ((tq ^ ((h0 + 1) >> 2)) & 15) + tr] = v.y;
      buf[(h0 + 2) * 64 + 4 * ((tq ^ ((h0 + 2) >> 2)) & 15) + tr] = v.z;
      buf[(h0 + 3) * 64 + 4 * ((tq ^ ((h0 + 3) >> 2)) & 15) + tr] = v.w;
    }
    __syncthreads();
    float4 acc = make_float4(0.f, 0.f, 0.f, 0.f);
    const float* arow = a_lds + sl * 128;
    #pragma unroll 8
    for (int hh = 0; hh < 64; ++hh) {
      int h = uh * 64 + hh;
      float ah = arow[h];
      float vh = vl[h];
      float4 p4 = *(const float4*)&buf[h * 64 + 4 * ((uq ^ ((h >> 2) & 15)) & 15)];
      acc.x = fmaf(vh, tanh_f(ah + p4.x), acc.x);
      acc.y = fmaf(vh, tanh_f(ah + p4.y), acc.y);
      acc.z = fmaf(vh, tanh_f(ah + p4.z), acc.z);
      acc.w = fmaf(vh, tanh_f(ah + p4.w), acc.w);
    }
    acc.x += __shfl_xor(acc.x, 16, 64);
    acc.y += __shfl_xor(acc.y, 16, 64);
    acc.z += __shfl_xor(acc.z, 16, 64);
    acc.w += __shfl_xor(acc.w, 16, 64);
    if (uh == 0) *(float4*)&sc[sl * 128 + tbase + 4 * uq] = acc;
  }
  __syncthreads();

  // ---- softmax over t (per s row; 32 lanes x f4 = 128) ----
  {
    float4 sv = *(const float4*)&sc[sl * 128 + 4 * u];
    float mx = fmaxf(fmaxf(sv.x, sv.y), fmaxf(sv.z, sv.w));
    #pragma unroll
    for (int msk = 1; msk <= 16; msk <<= 1) mx = fmaxf(mx, __shfl_xor(mx, msk, 64));
    float4 e;
    e.x = fexp2(LOG2E * (sv.x - mx));
    e.y = fexp2(LOG2E * (sv.y - mx));
    e.z = fexp2(LOG2E * (sv.z - mx));
    e.w = fexp2(LOG2E * (sv.w - mx));
    float sm = (e.x + e.y) + (e.z + e.w);
    #pragma unroll
    for (int msk = 1; msk <= 16; msk <<= 1) sm += __shfl_xor(sm, msk, 64);
    float r = frcp(sm);
    e.x *= r; e.y *= r; e.z *= r; e.w *= r;
    *(float4*)&sc[sl * 128 + 4 * u] = e;
  }

  // ---- ctx = w @ encH ----
  float4 ctx = make_float4(0.f, 0.f, 0.f, 0.f);
  const int h0c = 4 * u;
  for (int half = 0; half < 2; ++half) {
    const int tbase = half * 64;
    __syncthreads();  // buf reuse; also orders softmax writes before reads
    #pragma unroll
    for (int i = 0; i < 4; ++i) {
      int flat = i * 2048 + tid * 4;
      int tp = flat >> 7;
      int hh0 = flat & 127;
      *(float4*)&buf[tp * 128 + hh0] =
          *(const float4*)(encH + ((size_t)b * TT + tbase + tp) * HH + hh0);
    }
    __syncthreads();
    const float* wrow = sc + sl * 128 + tbase;
    #pragma unroll 8
    for (int tp = 0; tp < 64; ++tp) {
      float wt = wrow[tp];
      float4 e4 = *(const float4*)&buf[tp * 128 + h0c];
      FMA4S(ctx, wt, e4);
    }
  }
  __syncthreads();
  *(float4*)&a_lds[sl * 128 + h0c] = ctx;  // overlay A tile with ctx
  __syncthreads();

  // ---- out = [decH, ctx] @ outW^T + outb ----
  if (tid < 192) {
    int s = tid / 12, f = tid % 12;
    float acc = outb[f];
    const float4* w4 = (const float4*)(outW + f * 256);
    const float4* d4 = (const float4*)(dh + s * 128);
    const float4* c4 = (const float4*)(a_lds + s * 128);
    #pragma unroll
    for (int k = 0; k < 32; ++k) {
      float4 wv = w4[k], dv = d4[k];
      acc = fmaf(wv.x, dv.x, acc); acc = fmaf(wv.y, dv.y, acc);
      acc = fmaf(wv.z, dv.z, acc); acc = fmaf(wv.w, dv.w, acc);
    }
    #pragma unroll
    for (int k = 0; k < 32; ++k) {
      float4 wv = w4[32 + k], cv = c4[k];
      acc = fmaf(wv.x, cv.x, acc); acc = fmaf(wv.y, cv.y, acc);
      acc = fmaf(wv.z, cv.z, acc); acc = fmaf(wv.w, cv.w, acc);
    }
    out[((size_t)b * TT + s0 + s) * FIN + f] = acc;
  }
}

// ---------------------------------------------------------------------------
extern "C" void kernel_launch(void* const* d_in, const int* in_sizes, int n_in,
                              void* d_out, int out_size, void* d_ws, size_t ws_size,
                              hipStream_t stream)
{
  const float* x     = (const float*)d_in[0];
  const float* eWih  = (const float*)d_in[1];
  const float* eWhh  = (const float*)d_in[2];
  const float* eb    = (const float*)d_in[3];
  const float* dWih  = (const float*)d_in[4];
  const float* dWhh  = (const float*)d_in[5];
  const float* db    = (const float*)d_in[6];
  const float* attnW = (const float*)d_in[7];
  const float* attnb = (const float*)d_in[8];
  const float* vw    = (const float*)d_in[9];
  const float* outW  = (const float*)d_in[10];
  const float* outb  = (const float*)d_in[11];
  float* out = (float*)d_out;

  float* ws   = (float*)d_ws;
  const size_t SEG = (size_t)BB * TT * HH;  // 1,048,576 floats = 4 MB
  float* encH = ws;
  float* decH = ws + SEG;
  float* Abuf = ws + 2 * SEG;
  float* Pbuf = ws + 3 * SEG;

  lstm_kernel<<<64, 512, 0, stream>>>(x, eWih, eWhh, eb, dWih, dWhh, db, encH, decH);
  proj_kernel<<<1024, 256, 0, stream>>>(encH, decH, attnW, attnb, Abuf, Pbuf);
  attn_kernel<<<512, 512, 0, stream>>>(encH, decH, Abuf, Pbuf, vw, outW, outb, out);
}